// Round 7
// baseline (464.582 us; speedup 1.0000x reference)
//
#include <hip/hip_runtime.h>
#include <hip/hip_bf16.h>

// Problem constants
#define BB   2
#define SS   2048
#define HH   2048
#define NH   32
#define NKV  8
#define HD   64
#define NTOK (BB * SS)          // 4096
#define NQKV (NH * HD + 2 * NKV * HD)  // 3072
#define KOFF (NH * HD)          // 2048 (start of K cols)
#define VOFF (NH * HD + NKV * HD)      // 2560 (start of V cols)

// Q pre-scale: 1/sqrt(HD) * log2(e), so attn can use exp2 directly
#define QSC  0.1803368801111244f

typedef short  short8  __attribute__((ext_vector_type(8)));
typedef short  short4v __attribute__((ext_vector_type(4)));
typedef float  float4v __attribute__((ext_vector_type(4)));

using bf16 = __hip_bfloat16;

#define DEV static __device__ __forceinline__

DEV short8 load8(const bf16* p) { return *(const short8*)p; }
DEV short8 load8s(const short* p) { return *(const short8*)p; }

DEV short f2bfbits(float f) {
    union { bf16 h; short s; } u;
    u.h = __float2bfloat16(f);
    return u.s;
}

DEV unsigned int packbf2(float a, float b) {
    return (unsigned int)(unsigned short)f2bfbits(a)
         | ((unsigned int)(unsigned short)f2bfbits(b) << 16);
}

// async global->LDS, 16B per lane. ldsptr must be wave-uniform; HW writes
// lane l's 16 bytes at ldsptr + l*16.
DEV void async16(const bf16* g, short* l) {
    __builtin_amdgcn_global_load_lds(
        (const __attribute__((address_space(1))) unsigned int*)g,
        (__attribute__((address_space(3))) unsigned int*)l, 16, 0, 0);
}

// ---------------- fp32 -> bf16 convert, all tensors in ONE launch ----------
// Regions (element counts, all multiples of 1024): hidden 8M, q_w 4M,
// k_w 1M, v_w 1M, o_w 4M. Block = 256 thr x 4 elems = 1024 elems.
__global__ __launch_bounds__(256) void cvt_all_kernel(
    const float* __restrict__ hidden, const float* __restrict__ q_w,
    const float* __restrict__ k_w, const float* __restrict__ v_w,
    const float* __restrict__ o_w,
    bf16* __restrict__ Hb, bf16* __restrict__ Wqkv, bf16* __restrict__ Wo) {
    int blk = blockIdx.x;
    const float* src;
    bf16* dst;
    int off;
    if (blk < 8192)       { src = hidden; dst = Hb;   off = blk * 1024; }
    else if (blk < 12288) { src = q_w; dst = Wqkv;    off = (blk - 8192) * 1024; }
    else if (blk < 13312) { src = k_w; dst = Wqkv + (size_t)KOFF * HH; off = (blk - 12288) * 1024; }
    else if (blk < 14336) { src = v_w; dst = Wqkv + (size_t)VOFF * HH; off = (blk - 13312) * 1024; }
    else                  { src = o_w; dst = Wo;      off = (blk - 14336) * 1024; }
    int i = off + threadIdx.x * 4;
    float4 v = *(const float4*)(src + i);
    short4v o;
    o[0] = f2bfbits(v.x); o[1] = f2bfbits(v.y);
    o[2] = f2bfbits(v.z); o[3] = f2bfbits(v.w);
    *(short4v*)(dst + i) = o;
}
#define CVT_BLOCKS 18432

// ---------------- m97-style 128x128 GEMM mainloop ----------------
// C[m][n] = sum_k A[m][k] * Bw[n][k]  (both row-major, K-contiguous).
struct GemmCtx {
    const bf16 *gA0, *gA1, *gB0, *gB1;
    short *lA0, *lA1, *lB0, *lB1;
    const short *rdA, *rdB;
};

DEV void gemm_setup(GemmCtx& c, const bf16* A, const bf16* Bw, int K,
                    int m0, int n0, short* As, short* Bs) {
    int lane = threadIdx.x & 63, w = threadIdx.x >> 6;
    int quad = lane >> 4, tq = lane & 15;
    int srow = lane >> 2;
    int scol = (lane & 3) * 8;
    c.gA0 = A  + (size_t)(m0 + w * 32 + srow) * K + scol;
    c.gA1 = c.gA0 + (size_t)16 * K;
    c.gB0 = Bw + (size_t)(n0 + w * 32 + srow) * K + scol;
    c.gB1 = c.gB0 + (size_t)16 * K;
    c.lA0 = As + (w * 32) * 32;
    c.lA1 = As + (w * 32 + 16) * 32;
    c.lB0 = Bs + (w * 32) * 32;
    c.lB1 = Bs + (w * 32 + 16) * 32;
    int mbase = (w >> 1) * 64, nbase = (w & 1) * 64;
    c.rdA = As + (mbase + tq) * 32 + quad * 8;
    c.rdB = Bs + (nbase + tq) * 32 + quad * 8;
}

DEV void gemm_mainloop(GemmCtx& c, int K, float4v acc[4][4]) {
    for (int k0 = 0; k0 < K; k0 += 32) {
        __syncthreads();
        async16(c.gA0 + k0, c.lA0);
        async16(c.gA1 + k0, c.lA1);
        async16(c.gB0 + k0, c.lB0);
        async16(c.gB1 + k0, c.lB1);
        __syncthreads();
        short8 af[4], bfr[4];
#pragma unroll
        for (int mi = 0; mi < 4; ++mi) af[mi]  = *(const short8*)(c.rdA + mi * 16 * 32);
#pragma unroll
        for (int nj = 0; nj < 4; ++nj) bfr[nj] = *(const short8*)(c.rdB + nj * 16 * 32);
#pragma unroll
        for (int mi = 0; mi < 4; ++mi)
#pragma unroll
            for (int nj = 0; nj < 4; ++nj)
                acc[mi][nj] = __builtin_amdgcn_mfma_f32_16x16x32_bf16(
                    af[mi], bfr[nj], acc[mi][nj], 0, 0, 0);
    }
}

// ---------------- QKV projection + bias + RoPE ----------------
__global__ __launch_bounds__(256) void qkv_kernel(
    const bf16* __restrict__ Hb, const bf16* __restrict__ Wqkv,
    const float* __restrict__ qbias, const float* __restrict__ kbias,
    const float* __restrict__ vbias,
    const float* __restrict__ cosp, const float* __restrict__ sinp,
    const int* __restrict__ posp,
    bf16* __restrict__ Qb, bf16* __restrict__ Kb, bf16* __restrict__ Vt) {
    __shared__ __align__(16) short As[128 * 32];
    __shared__ __align__(16) short Bs[128 * 32];
    int lane = threadIdx.x & 63, w = threadIdx.x >> 6;
    int quad = lane >> 4, tq = lane & 15;
    int m0 = blockIdx.y * 128, n0 = blockIdx.x * 128;
    int mbase = (w >> 1) * 64, nbase = (w & 1) * 64;

    GemmCtx c;
    gemm_setup(c, Hb, Wqkv, HH, m0, n0, As, Bs);
    float4v acc[4][4] = {};
    gemm_mainloop(c, HH, acc);

    float biasv[4];
#pragma unroll
    for (int nj = 0; nj < 4; ++nj) {
        int colg = n0 + nbase + nj * 16 + tq;
        biasv[nj] = (colg < KOFF) ? qbias[colg]
                  : (colg < VOFF) ? kbias[colg - KOFF] : vbias[colg - VOFF];
    }

#pragma unroll
    for (int mi = 0; mi < 4; ++mi) {
#pragma unroll
        for (int r = 0; r < 4; ++r) {
            int tok = m0 + mbase + mi * 16 + quad * 4 + r;
            int p = posp[tok];
#pragma unroll
            for (int nj = 0; nj < 4; ++nj) {
                int colg = n0 + nbase + nj * 16 + tq;
                float val = acc[mi][nj][r] + biasv[nj];
                if (colg < VOFF) {
                    float pv = __shfl_xor(val, 1);
                    int jh = colg & 63;
                    float Cv = cosp[p * 32 + (jh & 31)];
                    float Sv = sinp[p * 32 + (jh & 31)];
                    float outv = (jh & 1) ? (val * Cv + pv * Sv)
                                          : (val * Cv - pv * Sv);
                    if (colg < KOFF)
                        // Q pre-scaled by 1/sqrt(HD)*log2e for exp2-softmax
                        Qb[(size_t)tok * (NH * HD) + colg] = __float2bfloat16(outv * QSC);
                    else
                        Kb[(size_t)tok * (NKV * HD) + (colg - KOFF)] = __float2bfloat16(outv);
                } else {
                    int c2 = colg - VOFF;
                    int kv = c2 >> 6, d = c2 & 63;
                    int bb = tok >> 11, s = tok & (SS - 1);
                    Vt[(((size_t)bb * NKV + kv) * HD + d) * SS + s] = __float2bfloat16(val);
                }
            }
        }
    }
}

// ---------------- output projection ----------------
__global__ __launch_bounds__(256) void oproj_kernel(
    const bf16* __restrict__ AO, const bf16* __restrict__ Wo,
    float* __restrict__ out) {
    __shared__ __align__(16) short As[128 * 32];
    __shared__ __align__(16) short Bs[128 * 32];
    int lane = threadIdx.x & 63, w = threadIdx.x >> 6;
    int quad = lane >> 4, tq = lane & 15;
    int m0 = blockIdx.y * 128, n0 = blockIdx.x * 128;
    int mbase = (w >> 1) * 64, nbase = (w & 1) * 64;

    GemmCtx c;
    gemm_setup(c, AO, Wo, NH * HD, m0, n0, As, Bs);
    float4v acc[4][4] = {};
    gemm_mainloop(c, NH * HD, acc);

#pragma unroll
    for (int mi = 0; mi < 4; ++mi) {
#pragma unroll
        for (int nj = 0; nj < 4; ++nj) {
            int colg = n0 + nbase + nj * 16 + tq;
#pragma unroll
            for (int r = 0; r < 4; ++r) {
                int tok = m0 + mbase + mi * 16 + quad * 4 + r;
                out[(size_t)tok * HH + colg] = acc[mi][nj][r];
            }
        }
    }
}

// ---------------- flash attention v6: shared-staging dual q-block -----------
// v5 cooperative LDS staging, but the complementary q-block pair (hi,lo)
// now shares ONE kv sweep: since hi's kv-range covers lo's, each staged
// K/V tile feeds both q-blocks. Staging steps/block: 33 -> 32-jq (avg 24.5).
// MFMA count unchanged; barriers and vmcnt drains cut ~26%.
#define PST 72   // P-tile LDS row stride in shorts

// One q-block's compute against the currently-staged K/V tile.
DEV void attn_work(bool mask, int kv0, int qw, int quad, int tq, int p0,
                   const short* Ks, const short* Vs, short* myp,
                   short8 aq0, short8 aq1, float4v ot[4], float& lsum) {
    // ---- scores S^T: lane holds S^T[kv=t*16+quad*4+r][q=tq] ----
    float4v st[4];
#pragma unroll
    for (int t = 0; t < 4; ++t) {
        const short* kr = Ks + (t * 16 + tq) * 64;
        short8 k0 = load8s(kr + p0);
        short8 k1 = load8s(kr + (p0 ^ 32));
        float4v s = {0.f, 0.f, 0.f, 0.f};
        s = __builtin_amdgcn_mfma_f32_16x16x32_bf16(k0, aq0, s, 0, 0, 0);
        s = __builtin_amdgcn_mfma_f32_16x16x32_bf16(k1, aq1, s, 0, 0, 0);
        st[t] = s;
    }

    // ---- exp2 + (optional) mask + per-lane row sum + pack -> P LDS ----
#pragma unroll
    for (int t = 0; t < 4; ++t) {
        float p[4];
#pragma unroll
        for (int r = 0; r < 4; ++r) {
            float e = __builtin_amdgcn_exp2f(st[t][r]);
            if (mask) {
                int kvg = kv0 + t * 16 + quad * 4 + r;
                e = (kvg <= qw) ? e : 0.f;
            }
            p[r] = e;
            lsum += e;
        }
        int pos = tq * PST + t * 16 + quad * 4;
        *(unsigned int*)(myp + pos)     = packbf2(p[0], p[1]);
        *(unsigned int*)(myp + pos + 2) = packbf2(p[2], p[3]);
    }

    // ---- read P B-frags (same-wave RAW; in-order DS pipe) ----
    short8 pf0 = load8s(myp + tq * PST + quad * 8);
    short8 pf1 = load8s(myp + tq * PST + 32 + quad * 8);

    // ---- PV: O^T[d][q] += V^T[d][kv] * P[q][kv] ----
#pragma unroll
    for (int i = 0; i < 4; ++i) {
        const short* vr = Vs + (i * 16 + tq) * 64;
        short8 bv0 = load8s(vr + p0);
        short8 bv1 = load8s(vr + (p0 ^ 32));
        ot[i] = __builtin_amdgcn_mfma_f32_16x16x32_bf16(bv0, pf0, ot[i], 0, 0, 0);
        ot[i] = __builtin_amdgcn_mfma_f32_16x16x32_bf16(bv1, pf1, ot[i], 0, 0, 0);
    }
}

DEV void attn_epilogue(int q0, int b, int h, int quad, int tq,
                       float4v ot[4], float lsum, bf16* __restrict__ AO) {
    lsum += __shfl_xor(lsum, 16);
    lsum += __shfl_xor(lsum, 32);
    float inv = 1.0f / lsum;
    bf16* obase = AO + (size_t)(b * SS + q0 + tq) * (NH * HD) + h * HD + quad * 4;
#pragma unroll
    for (int i = 0; i < 4; ++i) {
        short4v o;
#pragma unroll
        for (int r = 0; r < 4; ++r) o[r] = f2bfbits(ot[i][r] * inv);
        *(short4v*)(obase + i * 16) = o;
    }
}

// grid = (64, 16), block = 256. Block handles q-blocks hi=(31-jq)*64 and
// lo=jq*64 in ONE kv sweep (staged tiles shared). 1024 blocks = 4/CU.
__global__ __launch_bounds__(256, 4) void attn_kernel(
    const bf16* __restrict__ Qb, const bf16* __restrict__ Kb,
    const bf16* __restrict__ Vt, bf16* __restrict__ AO) {
    __shared__ __align__(16) short Ks[64 * 64];
    __shared__ __align__(16) short Vs[64 * 64];
    __shared__ __align__(16) short plds[4][16 * PST];

    int lane = threadIdx.x & 63, w = threadIdx.x >> 6;
    int quad = lane >> 4, tq = lane & 15;

    // XCD-aware swizzle (gridDim.x=64, XCD = flat%8 = blockIdx.x&7):
    // each XCD sees 2 (b,kvh) pairs -> ~1 MB K/V per 4 MB L2.
    int x = blockIdx.x;
    int xcd = x & 7, xi = x >> 3;
    int pair = xcd * 2 + (xi & 1);
    int b = pair >> 3, kvh = pair & 7;
    int h = kvh * 4 + (xi >> 1);

    const bf16* Kg = Kb + (size_t)(b * SS) * (NKV * HD) + kvh * HD;
    const bf16* Vg = Vt + (size_t)((b * NKV + kvh) * HD) * SS;
    short* myp = &plds[w][0];

    int jq = blockIdx.y;                 // 0..15
    int hi = (31 - jq) * 64, lo = jq * 64;

    // Q fragments for both q-blocks (each wave owns 16 rows of each block)
    const bf16* Qh = Qb + (size_t)(b * SS + hi + w * 16 + tq) * (NH * HD) + h * HD + quad * 8;
    const bf16* Ql = Qb + (size_t)(b * SS + lo + w * 16 + tq) * (NH * HD) + h * HD + quad * 8;
    short8 aqh0 = load8(Qh), aqh1 = load8(Qh + 32);
    short8 aql0 = load8(Ql), aql1 = load8(Ql + 32);

    int qwh = hi + w * 16 + tq;
    int qwl = lo + w * 16 + tq;

    float4v oth[4] = {}, otl[4] = {};
    float lsh = 0.f, lsl = 0.f;

    int srow = lane >> 3;                      // staging row within 8-row group
    int schunk = (lane & 7) ^ (srow & 7);      // swizzled 16B-chunk index
    int p0 = (quad ^ (tq & 7)) * 8;            // fragment-read physical offset

    for (int kv0 = 0; kv0 <= hi; kv0 += 64) {
        __syncthreads();   // prior step's LDS reads complete before overwrite
#pragma unroll
        for (int cc = 0; cc < 2; ++cc) {
            int rl = w * 16 + cc * 8;          // wave-uniform row base
            async16(Kg + (size_t)(kv0 + rl + srow) * (NKV * HD) + schunk * 8,
                    Ks + rl * 64);
            async16(Vg + (size_t)(rl + srow) * SS + kv0 + schunk * 8,
                    Vs + rl * 64);
        }
        __syncthreads();   // vmcnt drain: all 16 KB staged

        attn_work(kv0 == hi, kv0, qwh, quad, tq, p0, Ks, Vs, myp,
                  aqh0, aqh1, oth, lsh);
        if (kv0 <= lo)
            attn_work(kv0 == lo, kv0, qwl, quad, tq, p0, Ks, Vs, myp,
                      aql0, aql1, otl, lsl);
    }

    attn_epilogue(hi + w * 16, b, h, quad, tq, oth, lsh, AO);
    attn_epilogue(lo + w * 16, b, h, quad, tq, otl, lsl, AO);
}

extern "C" void kernel_launch(void* const* d_in, const int* in_sizes, int n_in,
                              void* d_out, int out_size, void* d_ws, size_t ws_size,
                              hipStream_t stream) {
    const float* hidden = (const float*)d_in[0];
    const float* cosp   = (const float*)d_in[1];
    const float* sinp   = (const float*)d_in[2];
    const int*   posp   = (const int*)d_in[3];
    // d_in[4] = mask (unused; causal mask applied analytically)
    const float* q_w = (const float*)d_in[5];
    const float* q_b = (const float*)d_in[6];
    const float* k_w = (const float*)d_in[7];
    const float* k_b = (const float*)d_in[8];
    const float* v_w = (const float*)d_in[9];
    const float* v_b = (const float*)d_in[10];
    const float* o_w = (const float*)d_in[11];
    float* out = (float*)d_out;

    char* ws = (char*)d_ws;
    bf16* Hb   = (bf16*)ws; ws += (size_t)NTOK * HH * 2;          // 16 MiB
    bf16* Wqkv = (bf16*)ws; ws += (size_t)NQKV * HH * 2;          // 12 MiB
    bf16* Wo   = (bf16*)ws; ws += (size_t)HH * (NH * HD) * 2;     // 8 MiB
    bf16* Qb   = (bf16*)ws; ws += (size_t)NTOK * (NH * HD) * 2;   // 16 MiB
    bf16* Kb   = (bf16*)ws; ws += (size_t)NTOK * (NKV * HD) * 2;  // 4 MiB
    bf16* Vt   = (bf16*)ws; ws += (size_t)NTOK * (NKV * HD) * 2;  // 4 MiB
    bf16* AO   = (bf16*)ws; ws += (size_t)NTOK * (NH * HD) * 2;   // 16 MiB

    // 1) all fp32->bf16 conversions in a single launch
    cvt_all_kernel<<<CVT_BLOCKS, 256, 0, stream>>>(
        hidden, q_w, k_w, v_w, o_w, Hb, Wqkv, Wo);

    // 2) fused QKV GEMM + bias + RoPE (+ V transpose)
    qkv_kernel<<<dim3(NQKV / 128, NTOK / 128), 256, 0, stream>>>(
        Hb, Wqkv, q_b, k_b, v_b, cosp, sinp, posp, Qb, Kb, Vt);

    // 3) flash attention (causal, GQA 4:1)
    attn_kernel<<<dim3(64, 16), 256, 0, stream>>>(Qb, Kb, Vt, AO);

    // 4) output projection -> fp32 out
    oproj_kernel<<<dim3(HH / 128, NTOK / 128), 256, 0, stream>>>(AO, Wo, out);
}

// Round 8
// 323.957 us; speedup vs baseline: 1.4341x; 1.4341x over previous
//
#include <hip/hip_runtime.h>
#include <hip/hip_bf16.h>

// Problem constants
#define BB   2
#define SS   2048
#define HH   2048
#define NH   32
#define NKV  8
#define HD   64
#define NTOK (BB * SS)          // 4096
#define NQKV (NH * HD + 2 * NKV * HD)  // 3072
#define KOFF (NH * HD)          // 2048 (start of K cols)
#define VOFF (NH * HD + NKV * HD)      // 2560 (start of V cols)

// Q pre-scale: 1/sqrt(HD) * log2(e), so attn can use exp2 directly
#define QSC  0.1803368801111244f

typedef short  short8  __attribute__((ext_vector_type(8)));
typedef short  short4v __attribute__((ext_vector_type(4)));
typedef float  float4v __attribute__((ext_vector_type(4)));

using bf16 = __hip_bfloat16;

#define DEV static __device__ __forceinline__

DEV short8 load8(const bf16* p) { return *(const short8*)p; }
DEV short8 load8s(const short* p) { return *(const short8*)p; }

DEV short f2bfbits(float f) {
    union { bf16 h; short s; } u;
    u.h = __float2bfloat16(f);
    return u.s;
}

DEV unsigned int packbf2(float a, float b) {
    return (unsigned int)(unsigned short)f2bfbits(a)
         | ((unsigned int)(unsigned short)f2bfbits(b) << 16);
}

// async global->LDS, 16B per lane. ldsptr must be wave-uniform; HW writes
// lane l's 16 bytes at ldsptr + l*16.
DEV void async16(const bf16* g, short* l) {
    __builtin_amdgcn_global_load_lds(
        (const __attribute__((address_space(1))) unsigned int*)g,
        (__attribute__((address_space(3))) unsigned int*)l, 16, 0, 0);
}

// ---------------- fp32 -> bf16 convert, all tensors in ONE launch ----------
// Regions (element counts, all multiples of 1024): hidden 8M, q_w 4M,
// k_w 1M, v_w 1M, o_w 4M. Block = 256 thr x 4 elems = 1024 elems.
__global__ __launch_bounds__(256) void cvt_all_kernel(
    const float* __restrict__ hidden, const float* __restrict__ q_w,
    const float* __restrict__ k_w, const float* __restrict__ v_w,
    const float* __restrict__ o_w,
    bf16* __restrict__ Hb, bf16* __restrict__ Wqkv, bf16* __restrict__ Wo) {
    int blk = blockIdx.x;
    const float* src;
    bf16* dst;
    int off;
    if (blk < 8192)       { src = hidden; dst = Hb;   off = blk * 1024; }
    else if (blk < 12288) { src = q_w; dst = Wqkv;    off = (blk - 8192) * 1024; }
    else if (blk < 13312) { src = k_w; dst = Wqkv + (size_t)KOFF * HH; off = (blk - 12288) * 1024; }
    else if (blk < 14336) { src = v_w; dst = Wqkv + (size_t)VOFF * HH; off = (blk - 13312) * 1024; }
    else                  { src = o_w; dst = Wo;      off = (blk - 14336) * 1024; }
    int i = off + threadIdx.x * 4;
    float4 v = *(const float4*)(src + i);
    short4v o;
    o[0] = f2bfbits(v.x); o[1] = f2bfbits(v.y);
    o[2] = f2bfbits(v.z); o[3] = f2bfbits(v.w);
    *(short4v*)(dst + i) = o;
}
#define CVT_BLOCKS 18432

// ---------------- m97-style 128x128 GEMM mainloop ----------------
// C[m][n] = sum_k A[m][k] * Bw[n][k]  (both row-major, K-contiguous).
struct GemmCtx {
    const bf16 *gA0, *gA1, *gB0, *gB1;
    short *lA0, *lA1, *lB0, *lB1;
    const short *rdA, *rdB;
};

DEV void gemm_setup(GemmCtx& c, const bf16* A, const bf16* Bw, int K,
                    int m0, int n0, short* As, short* Bs) {
    int lane = threadIdx.x & 63, w = threadIdx.x >> 6;
    int quad = lane >> 4, tq = lane & 15;
    int srow = lane >> 2;
    int scol = (lane & 3) * 8;
    c.gA0 = A  + (size_t)(m0 + w * 32 + srow) * K + scol;
    c.gA1 = c.gA0 + (size_t)16 * K;
    c.gB0 = Bw + (size_t)(n0 + w * 32 + srow) * K + scol;
    c.gB1 = c.gB0 + (size_t)16 * K;
    c.lA0 = As + (w * 32) * 32;
    c.lA1 = As + (w * 32 + 16) * 32;
    c.lB0 = Bs + (w * 32) * 32;
    c.lB1 = Bs + (w * 32 + 16) * 32;
    int mbase = (w >> 1) * 64, nbase = (w & 1) * 64;
    c.rdA = As + (mbase + tq) * 32 + quad * 8;
    c.rdB = Bs + (nbase + tq) * 32 + quad * 8;
}

DEV void gemm_mainloop(GemmCtx& c, int K, float4v acc[4][4]) {
    for (int k0 = 0; k0 < K; k0 += 32) {
        __syncthreads();
        async16(c.gA0 + k0, c.lA0);
        async16(c.gA1 + k0, c.lA1);
        async16(c.gB0 + k0, c.lB0);
        async16(c.gB1 + k0, c.lB1);
        __syncthreads();
        short8 af[4], bfr[4];
#pragma unroll
        for (int mi = 0; mi < 4; ++mi) af[mi]  = *(const short8*)(c.rdA + mi * 16 * 32);
#pragma unroll
        for (int nj = 0; nj < 4; ++nj) bfr[nj] = *(const short8*)(c.rdB + nj * 16 * 32);
#pragma unroll
        for (int mi = 0; mi < 4; ++mi)
#pragma unroll
            for (int nj = 0; nj < 4; ++nj)
                acc[mi][nj] = __builtin_amdgcn_mfma_f32_16x16x32_bf16(
                    af[mi], bfr[nj], acc[mi][nj], 0, 0, 0);
    }
}

// ---------------- QKV projection + bias + RoPE ----------------
__global__ __launch_bounds__(256) void qkv_kernel(
    const bf16* __restrict__ Hb, const bf16* __restrict__ Wqkv,
    const float* __restrict__ qbias, const float* __restrict__ kbias,
    const float* __restrict__ vbias,
    const float* __restrict__ cosp, const float* __restrict__ sinp,
    const int* __restrict__ posp,
    bf16* __restrict__ Qb, bf16* __restrict__ Kb, bf16* __restrict__ Vt) {
    __shared__ __align__(16) short As[128 * 32];
    __shared__ __align__(16) short Bs[128 * 32];
    int lane = threadIdx.x & 63, w = threadIdx.x >> 6;
    int quad = lane >> 4, tq = lane & 15;
    int m0 = blockIdx.y * 128, n0 = blockIdx.x * 128;
    int mbase = (w >> 1) * 64, nbase = (w & 1) * 64;

    GemmCtx c;
    gemm_setup(c, Hb, Wqkv, HH, m0, n0, As, Bs);
    float4v acc[4][4] = {};
    gemm_mainloop(c, HH, acc);

    float biasv[4];
#pragma unroll
    for (int nj = 0; nj < 4; ++nj) {
        int colg = n0 + nbase + nj * 16 + tq;
        biasv[nj] = (colg < KOFF) ? qbias[colg]
                  : (colg < VOFF) ? kbias[colg - KOFF] : vbias[colg - VOFF];
    }

#pragma unroll
    for (int mi = 0; mi < 4; ++mi) {
#pragma unroll
        for (int r = 0; r < 4; ++r) {
            int tok = m0 + mbase + mi * 16 + quad * 4 + r;
            int p = posp[tok];
#pragma unroll
            for (int nj = 0; nj < 4; ++nj) {
                int colg = n0 + nbase + nj * 16 + tq;
                float val = acc[mi][nj][r] + biasv[nj];
                if (colg < VOFF) {
                    float pv = __shfl_xor(val, 1);
                    int jh = colg & 63;
                    float Cv = cosp[p * 32 + (jh & 31)];
                    float Sv = sinp[p * 32 + (jh & 31)];
                    float outv = (jh & 1) ? (val * Cv + pv * Sv)
                                          : (val * Cv - pv * Sv);
                    if (colg < KOFF)
                        // Q pre-scaled by 1/sqrt(HD)*log2e for exp2-softmax
                        Qb[(size_t)tok * (NH * HD) + colg] = __float2bfloat16(outv * QSC);
                    else
                        Kb[(size_t)tok * (NKV * HD) + (colg - KOFF)] = __float2bfloat16(outv);
                } else {
                    int c2 = colg - VOFF;
                    int kv = c2 >> 6, d = c2 & 63;
                    int bb = tok >> 11, s = tok & (SS - 1);
                    Vt[(((size_t)bb * NKV + kv) * HD + d) * SS + s] = __float2bfloat16(val);
                }
            }
        }
    }
}

// ---------------- output projection ----------------
__global__ __launch_bounds__(256) void oproj_kernel(
    const bf16* __restrict__ AO, const bf16* __restrict__ Wo,
    float* __restrict__ out) {
    __shared__ __align__(16) short As[128 * 32];
    __shared__ __align__(16) short Bs[128 * 32];
    int lane = threadIdx.x & 63, w = threadIdx.x >> 6;
    int quad = lane >> 4, tq = lane & 15;
    int m0 = blockIdx.y * 128, n0 = blockIdx.x * 128;
    int mbase = (w >> 1) * 64, nbase = (w & 1) * 64;

    GemmCtx c;
    gemm_setup(c, AO, Wo, NH * HD, m0, n0, As, Bs);
    float4v acc[4][4] = {};
    gemm_mainloop(c, NH * HD, acc);

#pragma unroll
    for (int mi = 0; mi < 4; ++mi) {
#pragma unroll
        for (int nj = 0; nj < 4; ++nj) {
            int colg = n0 + nbase + nj * 16 + tq;
#pragma unroll
            for (int r = 0; r < 4; ++r) {
                int tok = m0 + mbase + mi * 16 + quad * 4 + r;
                out[(size_t)tok * HH + colg] = acc[mi][nj][r];
            }
        }
    }
}

// ---------------- flash attention v5: cooperative LDS staging ----------------
// (Reverted from v6 dual-q-block: doubling per-thread live state under the
// same 64-VGPR allocation caused massive scratch spills — WRITE_SIZE 16 MB ->
// 501 MB, attn 86 -> 208 us. v5 keeps ONE q-block's state per sweep.)
// Block = 4 waves, all processing the SAME 64-row q-block. Per kv-step of 64:
// K[64x64] and V^T[64x64] staged cooperatively via global_load_lds (no VGPR
// destinations -> no scheduler-serialized loads). 16B chunks XOR-swizzled on
// the global-address side so ds_read_b128 fragment reads are conflict-free.
// Complementary q-block pairing (jq <-> 31-jq) gives uniform 33 steps.
#define PST 72   // P-tile LDS row stride in shorts

template<bool MASK>
DEV void attn_kv_step(int kv0, int qw, int w, int lane, int quad, int tq,
                      const bf16* __restrict__ Kg, const bf16* __restrict__ Vg,
                      short* Ks, short* Vs, short* myp,
                      short8 aq0, short8 aq1,
                      float4v ot[4], float& lsum) {
    int srow = lane >> 3;                       // row within 8-row DMA group
    int schunk = (lane & 7) ^ (srow & 7);       // swizzled 16B-chunk index

    __syncthreads();   // prior step's LDS reads complete before overwrite
    // ---- stage K tile: rows kv0+w*16+c*8+srow, 8 elems at chunk schunk ----
#pragma unroll
    for (int cc = 0; cc < 2; ++cc) {
        int rl = w * 16 + cc * 8;               // wave-uniform row base
        async16(Kg + (size_t)(kv0 + rl + srow) * (NKV * HD) + schunk * 8,
                Ks + rl * 64);
        async16(Vg + (size_t)(rl + srow) * SS + kv0 + schunk * 8,
                Vs + rl * 64);
    }
    __syncthreads();   // vmcnt drain: all 16 KB staged

    // ---- scores S^T: lane holds S^T[kv=t*16+quad*4+r][q=tq] ----
    int p0 = (quad ^ (tq & 7)) * 8;             // physical chunk offsets
    float4v st[4];
#pragma unroll
    for (int t = 0; t < 4; ++t) {
        const short* kr = Ks + (t * 16 + tq) * 64;
        short8 k0 = load8s(kr + p0);
        short8 k1 = load8s(kr + (p0 ^ 32));
        float4v s = {0.f, 0.f, 0.f, 0.f};
        s = __builtin_amdgcn_mfma_f32_16x16x32_bf16(k0, aq0, s, 0, 0, 0);
        s = __builtin_amdgcn_mfma_f32_16x16x32_bf16(k1, aq1, s, 0, 0, 0);
        st[t] = s;
    }

    // ---- V^T frags: lane needs V^T[d=i*16+tq][kv=quad*8..] ----
    short8 bv[4][2];
#pragma unroll
    for (int i = 0; i < 4; ++i) {
        const short* vr = Vs + (i * 16 + tq) * 64;
        bv[i][0] = load8s(vr + p0);
        bv[i][1] = load8s(vr + (p0 ^ 32));
    }

    // ---- exp2 + mask + per-lane row sum + pack -> P LDS ----
#pragma unroll
    for (int t = 0; t < 4; ++t) {
        float p[4];
#pragma unroll
        for (int r = 0; r < 4; ++r) {
            float e = __builtin_amdgcn_exp2f(st[t][r]);
            if (MASK) {
                int kvg = kv0 + t * 16 + quad * 4 + r;
                e = (kvg <= qw) ? e : 0.f;
            }
            p[r] = e;
            lsum += e;
        }
        int pos = tq * PST + t * 16 + quad * 4;
        *(unsigned int*)(myp + pos)     = packbf2(p[0], p[1]);
        *(unsigned int*)(myp + pos + 2) = packbf2(p[2], p[3]);
    }

    // ---- read P B-frags (same-wave RAW; in-order DS pipe) ----
    short8 pf0 = load8s(myp + tq * PST + quad * 8);
    short8 pf1 = load8s(myp + tq * PST + 32 + quad * 8);

    // ---- PV: O^T[d][q] += V^T[d][kv] * P[q][kv] ----
#pragma unroll
    for (int i = 0; i < 4; ++i) {
        ot[i] = __builtin_amdgcn_mfma_f32_16x16x32_bf16(bv[i][0], pf0, ot[i], 0, 0, 0);
        ot[i] = __builtin_amdgcn_mfma_f32_16x16x32_bf16(bv[i][1], pf1, ot[i], 0, 0, 0);
    }
}

DEV void attn_qblock(int qb, int b, int h, int w, int lane, int quad, int tq,
                     const bf16* __restrict__ Qb,
                     const bf16* __restrict__ Kg, const bf16* __restrict__ Vg,
                     short* Ks, short* Vs, short* myp, bf16* __restrict__ AO) {
    int q0 = qb + w * 16;
    int qw = q0 + tq;
    const bf16* Qrow = Qb + (size_t)(b * SS + q0 + tq) * (NH * HD) + h * HD + quad * 8;
    short8 aq0 = load8(Qrow);
    short8 aq1 = load8(Qrow + 32);

    float4v ot[4] = {};
    float lsum = 0.f;

    for (int kv0 = 0; kv0 < qb; kv0 += 64)
        attn_kv_step<false>(kv0, qw, w, lane, quad, tq, Kg, Vg, Ks, Vs, myp,
                            aq0, aq1, ot, lsum);
    attn_kv_step<true>(qb, qw, w, lane, quad, tq, Kg, Vg, Ks, Vs, myp,
                       aq0, aq1, ot, lsum);

    // row sum: combine the 4 quads holding the same q=tq
    lsum += __shfl_xor(lsum, 16);
    lsum += __shfl_xor(lsum, 32);
    float inv = 1.0f / lsum;

    // epilogue: O^T[d=i*16+quad*4+r][q=tq]; r contiguous in d -> 8B stores
    bf16* obase = AO + (size_t)(b * SS + q0 + tq) * (NH * HD) + h * HD + quad * 4;
#pragma unroll
    for (int i = 0; i < 4; ++i) {
        short4v o;
#pragma unroll
        for (int r = 0; r < 4; ++r) o[r] = f2bfbits(ot[i][r] * inv);
        *(short4v*)(obase + i * 16) = o;
    }
}

// grid = (64, 16), block = 256. Block processes q-blocks (31-jq)*64 and jq*64
// -> uniform 33 kv-steps.
__global__ __launch_bounds__(256, 4) void attn_kernel(
    const bf16* __restrict__ Qb, const bf16* __restrict__ Kb,
    const bf16* __restrict__ Vt, bf16* __restrict__ AO) {
    __shared__ __align__(16) short Ks[64 * 64];
    __shared__ __align__(16) short Vs[64 * 64];
    __shared__ __align__(16) short plds[4][16 * PST];

    int lane = threadIdx.x & 63, w = threadIdx.x >> 6;
    int quad = lane >> 4, tq = lane & 15;

    // XCD-aware swizzle (gridDim.x=64, XCD = flat%8 = blockIdx.x&7):
    // each XCD sees 2 (b,kvh) pairs -> ~1 MB K/V per 4 MB L2.
    int x = blockIdx.x;
    int xcd = x & 7, xi = x >> 3;
    int pair = xcd * 2 + (xi & 1);
    int b = pair >> 3, kvh = pair & 7;
    int h = kvh * 4 + (xi >> 1);

    const bf16* Kg = Kb + (size_t)(b * SS) * (NKV * HD) + kvh * HD;
    const bf16* Vg = Vt + (size_t)((b * NKV + kvh) * HD) * SS;
    short* myp = &plds[w][0];

    int jq = blockIdx.y;                 // 0..15
    attn_qblock((31 - jq) * 64, b, h, w, lane, quad, tq, Qb, Kg, Vg, Ks, Vs, myp, AO);
    attn_qblock(jq * 64,        b, h, w, lane, quad, tq, Qb, Kg, Vg, Ks, Vs, myp, AO);
}

extern "C" void kernel_launch(void* const* d_in, const int* in_sizes, int n_in,
                              void* d_out, int out_size, void* d_ws, size_t ws_size,
                              hipStream_t stream) {
    const float* hidden = (const float*)d_in[0];
    const float* cosp   = (const float*)d_in[1];
    const float* sinp   = (const float*)d_in[2];
    const int*   posp   = (const int*)d_in[3];
    // d_in[4] = mask (unused; causal mask applied analytically)
    const float* q_w = (const float*)d_in[5];
    const float* q_b = (const float*)d_in[6];
    const float* k_w = (const float*)d_in[7];
    const float* k_b = (const float*)d_in[8];
    const float* v_w = (const float*)d_in[9];
    const float* v_b = (const float*)d_in[10];
    const float* o_w = (const float*)d_in[11];
    float* out = (float*)d_out;

    char* ws = (char*)d_ws;
    bf16* Hb   = (bf16*)ws; ws += (size_t)NTOK * HH * 2;          // 16 MiB
    bf16* Wqkv = (bf16*)ws; ws += (size_t)NQKV * HH * 2;          // 12 MiB
    bf16* Wo   = (bf16*)ws; ws += (size_t)HH * (NH * HD) * 2;     // 8 MiB
    bf16* Qb   = (bf16*)ws; ws += (size_t)NTOK * (NH * HD) * 2;   // 16 MiB
    bf16* Kb   = (bf16*)ws; ws += (size_t)NTOK * (NKV * HD) * 2;  // 4 MiB
    bf16* Vt   = (bf16*)ws; ws += (size_t)NTOK * (NKV * HD) * 2;  // 4 MiB
    bf16* AO   = (bf16*)ws; ws += (size_t)NTOK * (NH * HD) * 2;   // 16 MiB

    // 1) all fp32->bf16 conversions in a single launch
    cvt_all_kernel<<<CVT_BLOCKS, 256, 0, stream>>>(
        hidden, q_w, k_w, v_w, o_w, Hb, Wqkv, Wo);

    // 2) fused QKV GEMM + bias + RoPE (+ V transpose)
    qkv_kernel<<<dim3(NQKV / 128, NTOK / 128), 256, 0, stream>>>(
        Hb, Wqkv, q_b, k_b, v_b, cosp, sinp, posp, Qb, Kb, Vt);

    // 3) flash attention (causal, GQA 4:1)
    attn_kernel<<<dim3(64, 16), 256, 0, stream>>>(Qb, Kb, Vt, AO);

    // 4) output projection -> fp32 out
    oproj_kernel<<<dim3(HH / 128, NTOK / 128), 256, 0, stream>>>(AO, Wo, out);
}

// Round 9
// 296.298 us; speedup vs baseline: 1.5680x; 1.0933x over previous
//
#include <hip/hip_runtime.h>
#include <hip/hip_bf16.h>

// Problem constants
#define BB   2
#define SS   2048
#define HH   2048
#define NH   32
#define NKV  8
#define HD   64
#define NTOK (BB * SS)          // 4096
#define NQKV (NH * HD + 2 * NKV * HD)  // 3072
#define KOFF (NH * HD)          // 2048 (start of K cols)
#define VOFF (NH * HD + NKV * HD)      // 2560 (start of V cols)

// Q pre-scale: 1/sqrt(HD) * log2(e), so attn can use exp2 directly
#define QSC  0.1803368801111244f

typedef short  short8  __attribute__((ext_vector_type(8)));
typedef short  short4v __attribute__((ext_vector_type(4)));
typedef float  float4v __attribute__((ext_vector_type(4)));

using bf16 = __hip_bfloat16;

#define DEV static __device__ __forceinline__

DEV short8 load8(const bf16* p) { return *(const short8*)p; }
DEV short8 load8s(const short* p) { return *(const short8*)p; }

DEV short f2bfbits(float f) {
    union { bf16 h; short s; } u;
    u.h = __float2bfloat16(f);
    return u.s;
}

DEV unsigned int packbf2(float a, float b) {
    return (unsigned int)(unsigned short)f2bfbits(a)
         | ((unsigned int)(unsigned short)f2bfbits(b) << 16);
}

// async global->LDS, 16B per lane. ldsptr must be wave-uniform; HW writes
// lane l's 16 bytes at ldsptr + l*16.
DEV void async16(const bf16* g, short* l) {
    __builtin_amdgcn_global_load_lds(
        (const __attribute__((address_space(1))) unsigned int*)g,
        (__attribute__((address_space(3))) unsigned int*)l, 16, 0, 0);
}

// ---------------- fp32 -> bf16 convert, all tensors in ONE launch ----------
__global__ __launch_bounds__(256) void cvt_all_kernel(
    const float* __restrict__ hidden, const float* __restrict__ q_w,
    const float* __restrict__ k_w, const float* __restrict__ v_w,
    const float* __restrict__ o_w,
    bf16* __restrict__ Hb, bf16* __restrict__ Wqkv, bf16* __restrict__ Wo) {
    int blk = blockIdx.x;
    const float* src;
    bf16* dst;
    int off;
    if (blk < 8192)       { src = hidden; dst = Hb;   off = blk * 1024; }
    else if (blk < 12288) { src = q_w; dst = Wqkv;    off = (blk - 8192) * 1024; }
    else if (blk < 13312) { src = k_w; dst = Wqkv + (size_t)KOFF * HH; off = (blk - 12288) * 1024; }
    else if (blk < 14336) { src = v_w; dst = Wqkv + (size_t)VOFF * HH; off = (blk - 13312) * 1024; }
    else                  { src = o_w; dst = Wo;      off = (blk - 14336) * 1024; }
    int i = off + threadIdx.x * 4;
    float4 v = *(const float4*)(src + i);
    short4v o;
    o[0] = f2bfbits(v.x); o[1] = f2bfbits(v.y);
    o[2] = f2bfbits(v.z); o[3] = f2bfbits(v.w);
    *(short4v*)(dst + i) = o;
}
#define CVT_BLOCKS 18432

// ---------------- 128x128 GEMM mainloop, BK=64, XOR-swizzled LDS ----------
// C[m][n] = sum_k A[m][k] * Bw[n][k]  (both row-major, K-contiguous).
// BK=64 halves the barrier/vmcnt-drain count vs BK=32 (the m97 structural
// ~20% stall). Row stride is 128 B, so 16B chunks are XOR-swizzled
// (physical chunk = global chunk ^ (row&7)) on the GLOBAL address side at
// staging time; ds_read_b128 fragment reads then spread over all 8 bank
// groups. LDS 2 x 16 KB = 32 KB -> 3 blocks/CU (m132: 64 KB is the cliff).
struct GemmCtx {
    const bf16 *gA, *gB;      // per-lane swizzled global base (k0 added in loop)
    short *lA, *lB;           // wave-uniform LDS staging bases
    const short *rdA, *rdB;   // per-lane frag-read row bases (no chunk offset)
    int p0;                   // swizzled chunk byte-offset for kh=0
};

DEV void gemm_setup(GemmCtx& c, const bf16* A, const bf16* Bw, int K,
                    int m0, int n0, short* As, short* Bs) {
    int lane = threadIdx.x & 63, w = threadIdx.x >> 6;
    int quad = lane >> 4, tq = lane & 15;
    int srow = lane >> 3;                  // 0..7
    int schunk = (lane & 7) ^ srow;        // swizzled 16B-chunk index
    c.gA = A  + (size_t)(m0 + w * 32 + srow) * K + schunk * 8;
    c.gB = Bw + (size_t)(n0 + w * 32 + srow) * K + schunk * 8;
    c.lA = As + (w * 32) * 64;
    c.lB = Bs + (w * 32) * 64;
    int mbase = (w >> 1) * 64, nbase = (w & 1) * 64;
    c.rdA = As + (mbase + tq) * 64;
    c.rdB = Bs + (nbase + tq) * 64;
    c.p0 = (quad ^ (tq & 7)) * 8;
}

DEV void gemm_mainloop(GemmCtx& c, int K, float4v acc[4][4]) {
    for (int k0 = 0; k0 < K; k0 += 64) {
        __syncthreads();                     // prev reads done
#pragma unroll
        for (int cc = 0; cc < 4; ++cc) {
            async16(c.gA + (size_t)cc * 8 * K + k0, c.lA + cc * 8 * 64);
            async16(c.gB + (size_t)cc * 8 * K + k0, c.lB + cc * 8 * 64);
        }
        __syncthreads();                     // vmcnt drain: 32 KB staged
#pragma unroll
        for (int kh = 0; kh < 2; ++kh) {
            int off = c.p0 ^ (kh * 32);      // XOR, not add (swizzle)
            short8 af[4], bfr[4];
#pragma unroll
            for (int mi = 0; mi < 4; ++mi) af[mi]  = load8s(c.rdA + mi * 16 * 64 + off);
#pragma unroll
            for (int nj = 0; nj < 4; ++nj) bfr[nj] = load8s(c.rdB + nj * 16 * 64 + off);
#pragma unroll
            for (int mi = 0; mi < 4; ++mi)
#pragma unroll
                for (int nj = 0; nj < 4; ++nj)
                    acc[mi][nj] = __builtin_amdgcn_mfma_f32_16x16x32_bf16(
                        af[mi], bfr[nj], acc[mi][nj], 0, 0, 0);
        }
    }
}

// ---------------- QKV projection + bias + RoPE ----------------
__global__ __launch_bounds__(256, 3) void qkv_kernel(
    const bf16* __restrict__ Hb, const bf16* __restrict__ Wqkv,
    const float* __restrict__ qbias, const float* __restrict__ kbias,
    const float* __restrict__ vbias,
    const float* __restrict__ cosp, const float* __restrict__ sinp,
    const int* __restrict__ posp,
    bf16* __restrict__ Qb, bf16* __restrict__ Kb, bf16* __restrict__ Vt) {
    __shared__ __align__(16) short As[128 * 64];
    __shared__ __align__(16) short Bs[128 * 64];
    int lane = threadIdx.x & 63, w = threadIdx.x >> 6;
    int quad = lane >> 4, tq = lane & 15;
    int m0 = blockIdx.y * 128, n0 = blockIdx.x * 128;
    int mbase = (w >> 1) * 64, nbase = (w & 1) * 64;

    GemmCtx c;
    gemm_setup(c, Hb, Wqkv, HH, m0, n0, As, Bs);
    float4v acc[4][4] = {};
    gemm_mainloop(c, HH, acc);

    float biasv[4];
#pragma unroll
    for (int nj = 0; nj < 4; ++nj) {
        int colg = n0 + nbase + nj * 16 + tq;
        biasv[nj] = (colg < KOFF) ? qbias[colg]
                  : (colg < VOFF) ? kbias[colg - KOFF] : vbias[colg - VOFF];
    }

#pragma unroll
    for (int mi = 0; mi < 4; ++mi) {
#pragma unroll
        for (int r = 0; r < 4; ++r) {
            int tok = m0 + mbase + mi * 16 + quad * 4 + r;
            int p = posp[tok];
#pragma unroll
            for (int nj = 0; nj < 4; ++nj) {
                int colg = n0 + nbase + nj * 16 + tq;
                float val = acc[mi][nj][r] + biasv[nj];
                if (colg < VOFF) {
                    float pv = __shfl_xor(val, 1);
                    int jh = colg & 63;
                    float Cv = cosp[p * 32 + (jh & 31)];
                    float Sv = sinp[p * 32 + (jh & 31)];
                    float outv = (jh & 1) ? (val * Cv + pv * Sv)
                                          : (val * Cv - pv * Sv);
                    if (colg < KOFF)
                        // Q pre-scaled by 1/sqrt(HD)*log2e for exp2-softmax
                        Qb[(size_t)tok * (NH * HD) + colg] = __float2bfloat16(outv * QSC);
                    else
                        Kb[(size_t)tok * (NKV * HD) + (colg - KOFF)] = __float2bfloat16(outv);
                } else {
                    int c2 = colg - VOFF;
                    int kv = c2 >> 6, d = c2 & 63;
                    int bb = tok >> 11, s = tok & (SS - 1);
                    Vt[(((size_t)bb * NKV + kv) * HD + d) * SS + s] = __float2bfloat16(val);
                }
            }
        }
    }
}

// ---------------- output projection ----------------
__global__ __launch_bounds__(256, 3) void oproj_kernel(
    const bf16* __restrict__ AO, const bf16* __restrict__ Wo,
    float* __restrict__ out) {
    __shared__ __align__(16) short As[128 * 64];
    __shared__ __align__(16) short Bs[128 * 64];
    int lane = threadIdx.x & 63, w = threadIdx.x >> 6;
    int quad = lane >> 4, tq = lane & 15;
    int m0 = blockIdx.y * 128, n0 = blockIdx.x * 128;
    int mbase = (w >> 1) * 64, nbase = (w & 1) * 64;

    GemmCtx c;
    gemm_setup(c, AO, Wo, NH * HD, m0, n0, As, Bs);
    float4v acc[4][4] = {};
    gemm_mainloop(c, NH * HD, acc);

#pragma unroll
    for (int mi = 0; mi < 4; ++mi) {
#pragma unroll
        for (int nj = 0; nj < 4; ++nj) {
            int colg = n0 + nbase + nj * 16 + tq;
#pragma unroll
            for (int r = 0; r < 4; ++r) {
                int tok = m0 + mbase + mi * 16 + quad * 4 + r;
                out[(size_t)tok * HH + colg] = acc[mi][nj][r];
            }
        }
    }
}

// ---------------- flash attention v7: 32 q-rows per wave --------------------
// v5 cooperative staging (K[64x64], V^T[64x64] via global_load_lds, XOR-
// swizzled), but each wave now computes 32 q-rows (2 chunks of 16) per kv
// step: K/V LDS-read traffic per q-row HALVES (the binding resource), and
// staging traffic halves (512 blocks x 34 uniform steps instead of 1024x33).
// Superblocks of 128 q-rows processed SEQUENTIALLY (unlike v6's simultaneous
// dual state that spilled). LDS 34.8 KB -> LLVM's LDS-occupancy target is 4
// blocks/CU -> 128-VGPR budget; peak live ~110. launch_bounds(256,2) as a
// safety margin against the v6 spill heuristic.
#define PST 72   // P-tile LDS row stride in shorts

template<bool MASK>
DEV void attn_kv_step(int kv0, int qw0, int qw1, int w, int lane, int quad, int tq,
                      const bf16* __restrict__ Kg, const bf16* __restrict__ Vg,
                      short* Ks, short* Vs, short* myp,
                      const short8 (&aq)[2][2], float4v (&ot)[4][2], float (&ls)[2]) {
    int srow = lane >> 3;                       // row within 8-row DMA group
    int schunk = (lane & 7) ^ srow;             // swizzled 16B-chunk index

    __syncthreads();   // prior step's LDS reads complete before overwrite
#pragma unroll
    for (int cc = 0; cc < 2; ++cc) {
        int rl = w * 16 + cc * 8;               // wave-uniform row base
        async16(Kg + (size_t)(kv0 + rl + srow) * (NKV * HD) + schunk * 8,
                Ks + rl * 64);
        async16(Vg + (size_t)(rl + srow) * SS + kv0 + schunk * 8,
                Vs + rl * 64);
    }
    __syncthreads();   // vmcnt drain: all 16 KB staged

    int p0 = (quad ^ (tq & 7)) * 8;             // physical chunk offset

    // ---- scores S^T for both q-chunks; exp+pack per t to cap live regs ----
#pragma unroll
    for (int t = 0; t < 4; ++t) {
        const short* kr = Ks + (t * 16 + tq) * 64;
        short8 k0 = load8s(kr + p0);
        short8 k1 = load8s(kr + (p0 ^ 32));
        float4v s0 = {0.f, 0.f, 0.f, 0.f};
        float4v s1 = {0.f, 0.f, 0.f, 0.f};
        s0 = __builtin_amdgcn_mfma_f32_16x16x32_bf16(k0, aq[0][0], s0, 0, 0, 0);
        s0 = __builtin_amdgcn_mfma_f32_16x16x32_bf16(k1, aq[0][1], s0, 0, 0, 0);
        s1 = __builtin_amdgcn_mfma_f32_16x16x32_bf16(k0, aq[1][0], s1, 0, 0, 0);
        s1 = __builtin_amdgcn_mfma_f32_16x16x32_bf16(k1, aq[1][1], s1, 0, 0, 0);
#pragma unroll
        for (int qc = 0; qc < 2; ++qc) {
            const float4v& s = qc ? s1 : s0;
            int qw = qc ? qw1 : qw0;
            float p[4];
#pragma unroll
            for (int r = 0; r < 4; ++r) {
                float e = __builtin_amdgcn_exp2f(s[r]);
                if (MASK) {
                    int kvg = kv0 + t * 16 + quad * 4 + r;
                    e = (kvg <= qw) ? e : 0.f;
                }
                p[r] = e;
                ls[qc] += e;
            }
            int pos = (qc * 16 + tq) * PST + t * 16 + quad * 4;
            *(unsigned int*)(myp + pos)     = packbf2(p[0], p[1]);
            *(unsigned int*)(myp + pos + 2) = packbf2(p[2], p[3]);
        }
    }

    // ---- read P B-frags (same-wave RAW; in-order DS pipe) ----
    short8 pf00 = load8s(myp + tq * PST + quad * 8);
    short8 pf01 = load8s(myp + tq * PST + 32 + quad * 8);
    short8 pf10 = load8s(myp + (16 + tq) * PST + quad * 8);
    short8 pf11 = load8s(myp + (16 + tq) * PST + 32 + quad * 8);

    // ---- PV: O^T[d][q] += V^T[d][kv] * P[q][kv], both q-chunks ----
#pragma unroll
    for (int i = 0; i < 4; ++i) {
        const short* vr = Vs + (i * 16 + tq) * 64;
        short8 bv0 = load8s(vr + p0);
        short8 bv1 = load8s(vr + (p0 ^ 32));
        ot[i][0] = __builtin_amdgcn_mfma_f32_16x16x32_bf16(bv0, pf00, ot[i][0], 0, 0, 0);
        ot[i][0] = __builtin_amdgcn_mfma_f32_16x16x32_bf16(bv1, pf01, ot[i][0], 0, 0, 0);
        ot[i][1] = __builtin_amdgcn_mfma_f32_16x16x32_bf16(bv0, pf10, ot[i][1], 0, 0, 0);
        ot[i][1] = __builtin_amdgcn_mfma_f32_16x16x32_bf16(bv1, pf11, ot[i][1], 0, 0, 0);
    }
}

DEV void attn_superblock(int sb, int b, int h, int w, int lane, int quad, int tq,
                         const bf16* __restrict__ Qb,
                         const bf16* __restrict__ Kg, const bf16* __restrict__ Vg,
                         short* Ks, short* Vs, short* myp, bf16* __restrict__ AO) {
    // wave w owns q rows sb + w*32 .. +31, as two 16-row chunks
    int qw0 = sb + w * 32 + tq;
    int qw1 = qw0 + 16;
    const bf16* Qr0 = Qb + (size_t)(b * SS + qw0) * (NH * HD) + h * HD + quad * 8;
    const bf16* Qr1 = Qr0 + (size_t)16 * (NH * HD);
    short8 aq[2][2];
    aq[0][0] = load8(Qr0); aq[0][1] = load8(Qr0 + 32);
    aq[1][0] = load8(Qr1); aq[1][1] = load8(Qr1 + 32);

    float4v ot[4][2] = {};
    float ls[2] = {0.f, 0.f};

    for (int kv0 = 0; kv0 < sb; kv0 += 64)
        attn_kv_step<false>(kv0, qw0, qw1, w, lane, quad, tq, Kg, Vg, Ks, Vs, myp,
                            aq, ot, ls);
    attn_kv_step<true>(sb, qw0, qw1, w, lane, quad, tq, Kg, Vg, Ks, Vs, myp,
                       aq, ot, ls);
    attn_kv_step<true>(sb + 64, qw0, qw1, w, lane, quad, tq, Kg, Vg, Ks, Vs, myp,
                       aq, ot, ls);

#pragma unroll
    for (int qc = 0; qc < 2; ++qc) {
        float lsum = ls[qc];
        lsum += __shfl_xor(lsum, 16);
        lsum += __shfl_xor(lsum, 32);
        float inv = 1.0f / lsum;
        int qg = qc ? qw1 : qw0;
        bf16* obase = AO + (size_t)(b * SS + qg) * (NH * HD) + h * HD + quad * 4;
#pragma unroll
        for (int i = 0; i < 4; ++i) {
            short4v o;
#pragma unroll
            for (int r = 0; r < 4; ++r) o[r] = f2bfbits(ot[i][qc][r] * inv);
            *(short4v*)(obase + i * 16) = o;
        }
    }
}

// grid = (64, 8), block = 256. Block processes 128-row q-superblocks
// hi=(15-jq)*128 and lo=jq*128 sequentially -> uniform 34 kv-steps.
__global__ __launch_bounds__(256, 2) void attn_kernel(
    const bf16* __restrict__ Qb, const bf16* __restrict__ Kb,
    const bf16* __restrict__ Vt, bf16* __restrict__ AO) {
    __shared__ __align__(16) short Ks[64 * 64];
    __shared__ __align__(16) short Vs[64 * 64];
    __shared__ __align__(16) short plds[4][32 * PST];

    int lane = threadIdx.x & 63, w = threadIdx.x >> 6;
    int quad = lane >> 4, tq = lane & 15;

    // XCD-aware swizzle (gridDim.x=64, XCD = flat%8 = blockIdx.x&7):
    // each XCD sees 2 (b,kvh) pairs -> ~1 MB K/V per 4 MB L2.
    int x = blockIdx.x;
    int xcd = x & 7, xi = x >> 3;
    int pair = xcd * 2 + (xi & 1);
    int b = pair >> 3, kvh = pair & 7;
    int h = kvh * 4 + (xi >> 1);

    const bf16* Kg = Kb + (size_t)(b * SS) * (NKV * HD) + kvh * HD;
    const bf16* Vg = Vt + (size_t)((b * NKV + kvh) * HD) * SS;
    short* myp = &plds[w][0];

    int jq = blockIdx.y;                 // 0..7
    attn_superblock((15 - jq) * 128, b, h, w, lane, quad, tq, Qb, Kg, Vg, Ks, Vs, myp, AO);
    attn_superblock(jq * 128,        b, h, w, lane, quad, tq, Qb, Kg, Vg, Ks, Vs, myp, AO);
}

extern "C" void kernel_launch(void* const* d_in, const int* in_sizes, int n_in,
                              void* d_out, int out_size, void* d_ws, size_t ws_size,
                              hipStream_t stream) {
    const float* hidden = (const float*)d_in[0];
    const float* cosp   = (const float*)d_in[1];
    const float* sinp   = (const float*)d_in[2];
    const int*   posp   = (const int*)d_in[3];
    // d_in[4] = mask (unused; causal mask applied analytically)
    const float* q_w = (const float*)d_in[5];
    const float* q_b = (const float*)d_in[6];
    const float* k_w = (const float*)d_in[7];
    const float* k_b = (const float*)d_in[8];
    const float* v_w = (const float*)d_in[9];
    const float* v_b = (const float*)d_in[10];
    const float* o_w = (const float*)d_in[11];
    float* out = (float*)d_out;

    char* ws = (char*)d_ws;
    bf16* Hb   = (bf16*)ws; ws += (size_t)NTOK * HH * 2;          // 16 MiB
    bf16* Wqkv = (bf16*)ws; ws += (size_t)NQKV * HH * 2;          // 12 MiB
    bf16* Wo   = (bf16*)ws; ws += (size_t)HH * (NH * HD) * 2;     // 8 MiB
    bf16* Qb   = (bf16*)ws; ws += (size_t)NTOK * (NH * HD) * 2;   // 16 MiB
    bf16* Kb   = (bf16*)ws; ws += (size_t)NTOK * (NKV * HD) * 2;  // 4 MiB
    bf16* Vt   = (bf16*)ws; ws += (size_t)NTOK * (NKV * HD) * 2;  // 4 MiB
    bf16* AO   = (bf16*)ws; ws += (size_t)NTOK * (NH * HD) * 2;   // 16 MiB

    // 1) all fp32->bf16 conversions in a single launch
    cvt_all_kernel<<<CVT_BLOCKS, 256, 0, stream>>>(
        hidden, q_w, k_w, v_w, o_w, Hb, Wqkv, Wo);

    // 2) fused QKV GEMM + bias + RoPE (+ V transpose)
    qkv_kernel<<<dim3(NQKV / 128, NTOK / 128), 256, 0, stream>>>(
        Hb, Wqkv, q_b, k_b, v_b, cosp, sinp, posp, Qb, Kb, Vt);

    // 3) flash attention (causal, GQA 4:1)
    attn_kernel<<<dim3(64, 8), 256, 0, stream>>>(Qb, Kb, Vt, AO);

    // 4) output projection -> fp32 out
    oproj_kernel<<<dim3(HH / 128, NTOK / 128), 256, 0, stream>>>(AO, Wo, out);
}